// Round 1
// baseline (225.409 us; speedup 1.0000x reference)
//
#include <hip/hip_runtime.h>

#define HH 1024
#define WW 1024
#define NPTS 512          // 16 segments * 32 samples = path points = edges
#define CUT 14.0f         // sigmoid saturation cutoff: sigma(14) ~ 1 - 8e-7

__device__ __forceinline__ float sigmoidf(float z) {
    // 1/(1+exp(-z)); __expf overflows to +inf for very negative z -> returns 0. Correct saturation.
    float e = __expf(-z);
    return __builtin_amdgcn_rcpf(1.0f + e);
}

__global__ __launch_bounds__(256) void render_kernel(
    const float* __restrict__ cp,     // 49 x 2 control points
    const float* __restrict__ color,  // 3 floats
    float* __restrict__ out)          // H x W x 4
{
    __shared__ float2 pts[NPTS];
    __shared__ float2 ew[NPTS];   // .x = x_cross, .y = weight (valid_t * coeff)

    const int tid = threadIdx.x;
    const int y = blockIdx.x;
    const float yf = (float)y;

    // --- 1. Bezier path points (2 per thread) ---
    for (int i = tid; i < NPTS; i += 256) {
        int seg = i >> 5;
        int j = i & 31;
        float t = (float)j / 31.0f;           // linspace(0,1,32); exact 1.0 at j=31
        float mt = 1.0f - t;
        int b = 3 * seg * 2;
        float p0x = cp[b + 0], p0y = cp[b + 1];
        float p1x = cp[b + 2], p1y = cp[b + 3];
        float p2x = cp[b + 4], p2y = cp[b + 5];
        float p3x = cp[b + 6], p3y = cp[b + 7];
        float a0 = mt * mt * mt;
        float a1 = 3.0f * mt * mt * t;
        float a2 = 3.0f * mt * t * t;
        float a3 = t * t * t;
        pts[i] = make_float2(a0 * p0x + a1 * p1x + a2 * p2x + a3 * p3x,
                             a0 * p0y + a1 * p1y + a2 * p2y + a3 * p3y);
    }
    __syncthreads();

    // --- 2. per-edge, per-row crossing data ---
    for (int e = tid; e < NPTS; e += 256) {
        float2 p = pts[e];
        float2 q = pts[(e + 1) & (NPTS - 1)];
        float dy = q.y - p.y;
        float dx = q.x - p.x;
        float c = (dy > 0.0f) ? 1.0f : ((dy < 0.0f) ? -1.0f : 0.0f);
        if (fabsf(dy) < 1e-6f) c = 0.0f;
        float t = (yf - p.y) / (dy + 1e-8f);
        float xc = p.x + t * dx;
        float vt = sigmoidf(t * 20.0f) * sigmoidf((1.0f - t) * 20.0f);
        ew[e] = make_float2(xc, vt * c);
    }
    __syncthreads();

    // --- 3. pixel sweep: each wave handles 4 tiles of 64 consecutive px ---
    const float r = color[0], g = color[1], b = color[2];
    const int wave = tid >> 6;
    const int lane = tid & 63;

    for (int tile = 0; tile < 4; ++tile) {
        const int base = tile * 256 + wave * 64;
        const int x = base + lane;
        const float xf = (float)x;
        const float basef = (float)base;
        float acc = 0.0f;

        for (int e = 0; e < NPTS; ++e) {
            float2 d = ew[e];
            float rel = d.x - basef;        // wave-uniform (d.x uniform, basef uniform)
            if (rel >= 63.0f + CUT) {
                // all 64 lanes saturated high: sigma ~= 1
                acc += d.y;
            } else if (rel > -CUT) {
                // transition window touches this tile: exact eval
                float z = d.x - xf;
                float s = sigmoidf(z);
                acc = fmaf(d.y, s, acc);
            }
            // else: all lanes sigma ~= 0, skip
        }

        float alpha = sigmoidf(4.0f * acc);
        ((float4*)out)[y * WW + x] = make_float4(r, g, b, alpha);
    }
}

extern "C" void kernel_launch(void* const* d_in, const int* in_sizes, int n_in,
                              void* d_out, int out_size, void* d_ws, size_t ws_size,
                              hipStream_t stream) {
    const float* cp = (const float*)d_in[0];
    const float* color = (const float*)d_in[1];
    float* out = (float*)d_out;
    render_kernel<<<HH, 256, 0, stream>>>(cp, color, out);
}

// Round 2
// 67.964 us; speedup vs baseline: 3.3166x; 3.3166x over previous
//
#include <hip/hip_runtime.h>

#define HH 1024
#define WW 1024
#define NPTS 512          // 16 segments * 32 samples = path points = edges
#define W_EPS 1e-6f       // drop edges whose weight is below this (err <= 512*eps)

__device__ __forceinline__ float sigmoidf(float z) {
    // 1/(1+exp(-z)); __expf overflows to +inf for very negative z -> returns 0.
    float e = __expf(-z);
    return __builtin_amdgcn_rcpf(1.0f + e);
}

__global__ __launch_bounds__(256) void render_kernel(
    const float* __restrict__ cp,     // 49 x 2 control points
    const float* __restrict__ color,  // 3 floats
    float* __restrict__ out)          // H x W x 4
{
    __shared__ float2 pts[NPTS];
    __shared__ float2 act[NPTS];      // compacted (x_cross, weight) for this row
    __shared__ int n_act;

    const int tid = threadIdx.x;
    const int y = blockIdx.x;
    const float yf = (float)y;

    if (tid == 0) n_act = 0;

    // --- 1. Bezier path points (2 per thread) ---
    for (int i = tid; i < NPTS; i += 256) {
        int seg = i >> 5;
        int j = i & 31;
        float t = (float)j / 31.0f;           // linspace(0,1,32)
        float mt = 1.0f - t;
        int b = 3 * seg * 2;
        float p0x = cp[b + 0], p0y = cp[b + 1];
        float p1x = cp[b + 2], p1y = cp[b + 3];
        float p2x = cp[b + 4], p2y = cp[b + 5];
        float p3x = cp[b + 6], p3y = cp[b + 7];
        float a0 = mt * mt * mt;
        float a1 = 3.0f * mt * mt * t;
        float a2 = 3.0f * mt * t * t;
        float a3 = t * t * t;
        pts[i] = make_float2(a0 * p0x + a1 * p1x + a2 * p2x + a3 * p3x,
                             a0 * p0y + a1 * p1y + a2 * p2y + a3 * p3y);
    }
    __syncthreads();

    // --- 2. per-edge weight for this row; compact the active ones ---
    for (int e = tid; e < NPTS; e += 256) {
        float2 p = pts[e];
        float2 q = pts[(e + 1) & (NPTS - 1)];
        float dy = q.y - p.y;
        float dx = q.x - p.x;
        float c = (dy > 0.0f) ? 1.0f : ((dy < 0.0f) ? -1.0f : 0.0f);
        if (fabsf(dy) < 1e-6f) c = 0.0f;
        float t = (yf - p.y) / (dy + 1e-8f);
        float vt = sigmoidf(t * 20.0f) * sigmoidf((1.0f - t) * 20.0f);
        float w = vt * c;
        if (fabsf(w) > W_EPS) {
            float xc = p.x + t * dx;
            int idx = atomicAdd(&n_act, 1);
            act[idx] = make_float2(xc, w);
        }
    }
    __syncthreads();

    const int n = n_act;   // block-uniform
    const float r = color[0], g = color[1], b = color[2];

    // --- 3. pixel sweep: 4 px per thread (x = k*256 + tid), branch-free ---
    float acc0 = 0.0f, acc1 = 0.0f, acc2 = 0.0f, acc3 = 0.0f;
    const float x0 = (float)tid;
    const float x1 = (float)(256 + tid);
    const float x2 = (float)(512 + tid);
    const float x3 = (float)(768 + tid);

    for (int e = 0; e < n; ++e) {
        float2 d = act[e];            // wave-uniform broadcast read
        acc0 = fmaf(d.y, sigmoidf(d.x - x0), acc0);
        acc1 = fmaf(d.y, sigmoidf(d.x - x1), acc1);
        acc2 = fmaf(d.y, sigmoidf(d.x - x2), acc2);
        acc3 = fmaf(d.y, sigmoidf(d.x - x3), acc3);
    }

    float4* orow = ((float4*)out) + y * WW;
    orow[tid]       = make_float4(r, g, b, sigmoidf(4.0f * acc0));
    orow[256 + tid] = make_float4(r, g, b, sigmoidf(4.0f * acc1));
    orow[512 + tid] = make_float4(r, g, b, sigmoidf(4.0f * acc2));
    orow[768 + tid] = make_float4(r, g, b, sigmoidf(4.0f * acc3));
}

extern "C" void kernel_launch(void* const* d_in, const int* in_sizes, int n_in,
                              void* d_out, int out_size, void* d_ws, size_t ws_size,
                              hipStream_t stream) {
    const float* cp = (const float*)d_in[0];
    const float* color = (const float*)d_in[1];
    float* out = (float*)d_out;
    render_kernel<<<HH, 256, 0, stream>>>(cp, color, out);
}

// Round 3
// 64.559 us; speedup vs baseline: 3.4915x; 1.0527x over previous
//
#include <hip/hip_runtime.h>

#define HH 1024
#define WW 1024
#define NPTS 512          // 16 segments * 32 samples = path points = edges
#define W_EPS 1e-6f       // drop edges whose row-weight is below this (err <= 512*eps)
#define CAP 64            // per-tile bucket capacity (fallback path if exceeded)

__device__ __forceinline__ float sigmoidf(float z) {
    // 1/(1+exp(-z)); __expf underflows to 0 for very negative z -> sigmoid==1 exactly. OK.
    float e = __expf(-z);
    return __builtin_amdgcn_rcpf(1.0f + e);
}

__global__ __launch_bounds__(256) void render_kernel(
    const float* __restrict__ cp,     // 49 x 2 control points
    const float* __restrict__ color,  // 3 floats
    float* __restrict__ out)          // H x W x 4
{
    __shared__ float2 pts[NPTS];
    __shared__ float2 actXW[NPTS];    // compacted (x_cross, w)
    __shared__ int    actTmin[NPTS];  // tiles t < tmin: edge fully saturated (acc += w)
    __shared__ int    actTmax[NPTS];  // tiles in [tmin, tmax]: transition window (eval sigma)
    __shared__ float2 bucket[16][CAP];
    __shared__ int    cnt[16];
    __shared__ float  satW[16];
    __shared__ int    n_act;

    const int tid = threadIdx.x;
    const int y = blockIdx.x;
    const float yf = (float)y;

    if (tid == 0) n_act = 0;
    if (tid < 16) cnt[tid] = 0;

    // --- 1. Bezier path points (2 per thread) ---
    for (int i = tid; i < NPTS; i += 256) {
        int seg = i >> 5;
        int j = i & 31;
        float t = (float)j / 31.0f;           // linspace(0,1,32)
        float mt = 1.0f - t;
        int bb = 3 * seg * 2;
        float p0x = cp[bb + 0], p0y = cp[bb + 1];
        float p1x = cp[bb + 2], p1y = cp[bb + 3];
        float p2x = cp[bb + 4], p2y = cp[bb + 5];
        float p3x = cp[bb + 6], p3y = cp[bb + 7];
        float a0 = mt * mt * mt;
        float a1 = 3.0f * mt * mt * t;
        float a2 = 3.0f * mt * t * t;
        float a3 = t * t * t;
        pts[i] = make_float2(a0 * p0x + a1 * p1x + a2 * p2x + a3 * p3x,
                             a0 * p0y + a1 * p1y + a2 * p2y + a3 * p3y);
    }
    __syncthreads();

    // --- 2. per-edge weight for this row; compact + classify per 64-px tile ---
    // tile t covers x in [64t, 64t+63].
    //   saturated for all x in tile  <=> xc >= 64t+63+14  (sigma >= 1-8e-7)
    //   negligible for all x in tile <=> xc <= 64t-14     (sigma <= 8e-7)
    // satW membership (t < tmin) and bucket membership (tmin<=t<=tmax) use the
    // SAME integer tmin -> mutually exclusive, no double count at boundaries.
    for (int e = tid; e < NPTS; e += 256) {
        float2 p = pts[e];
        float2 q = pts[(e + 1) & (NPTS - 1)];
        float dy = q.y - p.y;
        float dx = q.x - p.x;
        float c = (dy > 0.0f) ? 1.0f : ((dy < 0.0f) ? -1.0f : 0.0f);
        if (fabsf(dy) < 1e-6f) c = 0.0f;
        float t = (yf - p.y) / (dy + 1e-8f);
        float vt = sigmoidf(t * 20.0f) * sigmoidf((1.0f - t) * 20.0f);
        float w = vt * c;
        if (fabsf(w) > W_EPS) {
            float xc = p.x + t * dx;
            int tmin = (int)ceilf((xc - 77.0f) * 0.015625f);   // /64
            if (tmin < 0) tmin = 0;
            if (tmin > 16) tmin = 16;
            int tmax = (int)floorf((xc + 14.0f) * 0.015625f);
            if (tmax > 15) tmax = 15;
            int idx = atomicAdd(&n_act, 1);
            actXW[idx] = make_float2(xc, w);
            actTmin[idx] = tmin;
            actTmax[idx] = tmax;
            for (int tt = tmin; tt <= tmax; ++tt) {
                int pos = atomicAdd(&cnt[tt], 1);
                if (pos < CAP) bucket[tt][pos] = make_float2(xc, w);
            }
        }
    }
    __syncthreads();

    const int n = n_act;   // block-uniform

    // --- 2c. per-tile saturated sum: satW[t] = sum of w over edges with t < tmin ---
    {
        int grp = tid >> 4;        // tile 0..15
        int l16 = tid & 15;
        float partial = 0.0f;
        for (int i = l16; i < n; i += 16)
            if (grp < actTmin[i]) partial += actXW[i].y;
        partial += __shfl_down(partial, 8, 16);
        partial += __shfl_down(partial, 4, 16);
        partial += __shfl_down(partial, 2, 16);
        partial += __shfl_down(partial, 1, 16);
        if (l16 == 0) satW[grp] = partial;
    }
    __syncthreads();

    // --- 3. pixel sweep: wave wv handles tiles {wv, wv+4, wv+8, wv+12} ---
    const float cr = color[0], cg = color[1], cb = color[2];
    const int wv = tid >> 6;
    const int lane = tid & 63;
    float4* orow = ((float4*)out) + y * WW;

    for (int k = 0; k < 4; ++k) {
        const int t = k * 4 + wv;
        const int x = t * 64 + lane;
        const float xf = (float)x;
        float acc;
        const int m = cnt[t];
        if (m <= CAP) {
            acc = satW[t];
            for (int j = 0; j < m; ++j) {
                float2 d = bucket[t][j];            // wave-uniform broadcast
                acc = fmaf(d.y, sigmoidf(d.x - xf), acc);
            }
        } else {
            // overflow fallback: classified scan of the full compact list
            acc = 0.0f;
            for (int i = 0; i < n; ++i) {
                int tmin = actTmin[i];
                if (t < tmin) {
                    acc += actXW[i].y;
                } else if (t <= actTmax[i]) {
                    float2 d = actXW[i];
                    acc = fmaf(d.y, sigmoidf(d.x - xf), acc);
                }
            }
        }
        orow[x] = make_float4(cr, cg, cb, sigmoidf(4.0f * acc));
    }
}

extern "C" void kernel_launch(void* const* d_in, const int* in_sizes, int n_in,
                              void* d_out, int out_size, void* d_ws, size_t ws_size,
                              hipStream_t stream) {
    const float* cp = (const float*)d_in[0];
    const float* color = (const float*)d_in[1];
    float* out = (float*)d_out;
    render_kernel<<<HH, 256, 0, stream>>>(cp, color, out);
}